// Round 1
// baseline (27483.325 us; speedup 1.0000x reference)
//
#include <hip/hip_runtime.h>

typedef __attribute__((ext_vector_type(8))) short s16x8;
typedef __attribute__((ext_vector_type(4))) float f32x4;

#define S_LEN 2048
#define H_DIM 512
#define I_DIM 128
// ws layout: [0,4096)  barrier counters (8 groups, 256B stride)
//            [4096, 4096+2*128*512*4)  h double-buffer, u32 words = (bf16_hi | bf16_lo<<16)

__device__ __forceinline__ unsigned short bf16_rne(float f){
  unsigned u = __builtin_bit_cast(unsigned, f);
  u += 0x7FFFu + ((u >> 16) & 1u);
  return (unsigned short)(u >> 16);
}
__device__ __forceinline__ float bf16_to_f(unsigned short h){
  unsigned u = ((unsigned)h) << 16;
  return __builtin_bit_cast(float, u);
}
__device__ __forceinline__ float sigm(float x){
  return 1.f / (1.f + __builtin_exp2f(-1.44269504f * x));
}
__device__ __forceinline__ float tanh_f(float x){
  float t = __builtin_exp2f(2.88539008f * x);
  return 1.f - 2.f / (t + 1.f);   // robust: t->inf => 1, t->0 => -1
}

// split 8 consecutive fp32 into hi/lo bf16 fragments
__device__ __forceinline__ void split8(const float* __restrict__ src, s16x8& hi, s16x8& lo){
  const float4* p4 = (const float4*)src;
  float4 a = p4[0], b = p4[1];
  float v[8] = {a.x, a.y, a.z, a.w, b.x, b.y, b.z, b.w};
  #pragma unroll
  for (int e = 0; e < 8; ++e){
    unsigned short h = bf16_rne(v[e]);
    float r = v[e] - bf16_to_f(h);
    hi[e] = (short)h;
    lo[e] = (short)bf16_rne(r);
  }
}

__global__ void __launch_bounds__(256, 1)
lstm_scan_kernel(const float* __restrict__ x,
                 const float* __restrict__ Wh,
                 const float* __restrict__ Wx,
                 const float* __restrict__ bias,
                 unsigned* __restrict__ hw_buf,     // [2][128][512] u32 words
                 unsigned* __restrict__ barriers)   // 8 counters @ 256B stride
{
  __shared__ float exch[1024];                      // [gate(4)][b_local(16)][j_local(16)]

  const int tid  = threadIdx.x;
  const int wg   = blockIdx.x;
  const int grp  = wg & 7;        // batch group (XCD-friendly: %8)
  const int sl   = wg >> 3;       // j-slice 0..31
  const int lane = tid & 63;
  const int w    = tid >> 6;      // wave 0..3 owns K-chunk [w*160, ...)
  const int l15  = lane & 15;     // A-row (batch-local) / B-col (j-local) / D-col
  const int kq   = lane >> 4;     // k quarter 0..3
  const int bbase = grp * 16;
  const int jglob = sl * 16 + l15;

  // ---- persistent weight fragments in registers (split bf16 hi/lo) ----
  // B-frag for mfma_f32_16x16x32_bf16: lane holds B[k0+kq*8+e][l15] = W[rowbase+l15][k0+kq*8+e]
  s16x8 Whi[4][4], Wlo[4][4];       // [kt][gate]
  s16x8 Xhi_w[4], Xlo_w[4];         // [gate], x-part K-chunk of this wave
  #pragma unroll
  for (int g = 0; g < 4; ++g){
    const int row = 512 * g + sl * 16 + l15;
    #pragma unroll
    for (int kt = 0; kt < 4; ++kt){
      const float* src = Wh + (size_t)row * 512 + (4 * w + kt) * 32 + kq * 8;
      split8(src, Whi[kt][g], Wlo[kt][g]);
    }
    const float* sx = Wx + (size_t)row * 128 + w * 32 + kq * 8;
    split8(sx, Xhi_w[g], Xlo_w[g]);
  }

  float bias_r[4];
  #pragma unroll
  for (int g = 0; g < 4; ++g) bias_r[g] = bias[512 * g + jglob];

  float cpriv[4] = {0.f, 0.f, 0.f, 0.f};   // used by wave 0 only: c for (b=bbase+4*kq+r, j=jglob)
  unsigned* cnt = (unsigned*)((char*)barriers + grp * 256);
  unsigned cur = 0;

  for (int t = 0; t < S_LEN; ++t){
    // zero the LDS exchange
    #pragma unroll
    for (int i = 0; i < 4; ++i) exch[tid * 4 + i] = 0.f;

    // issue h word loads early (coherent/agent loads, 2 words per u64)
    unsigned long long hwv[4][4];
    const unsigned* hb = hw_buf + cur * 65536u + (unsigned)(bbase + l15) * 512u;
    #pragma unroll
    for (int kt = 0; kt < 4; ++kt){
      unsigned long long* p = (unsigned long long*)(hb + (4 * w + kt) * 32 + kq * 8);
      #pragma unroll
      for (int q = 0; q < 4; ++q)
        hwv[kt][q] = __hip_atomic_load(p + q, __ATOMIC_RELAXED, __HIP_MEMORY_SCOPE_AGENT);
    }

    __syncthreads();   // exch zero visible before ds_adds

    f32x4 acc[4];
    #pragma unroll
    for (int g = 0; g < 4; ++g){ f32x4 z = {0.f, 0.f, 0.f, 0.f}; acc[g] = z; }

    // ---- x part (overlaps h-load latency) ----
    {
      const float* xsrc = x + ((size_t)(bbase + l15) * S_LEN + t) * I_DIM + w * 32 + kq * 8;
      s16x8 xhi, xlo; split8(xsrc, xhi, xlo);
      #pragma unroll
      for (int g = 0; g < 4; ++g){
        acc[g] = __builtin_amdgcn_mfma_f32_16x16x32_bf16(xhi, Xhi_w[g], acc[g], 0, 0, 0);
        acc[g] = __builtin_amdgcn_mfma_f32_16x16x32_bf16(xlo, Xhi_w[g], acc[g], 0, 0, 0);
        acc[g] = __builtin_amdgcn_mfma_f32_16x16x32_bf16(xhi, Xlo_w[g], acc[g], 0, 0, 0);
      }
    }

    // ---- h part: unpack words -> hi/lo A-frags, 3 split products ----
    #pragma unroll
    for (int kt = 0; kt < 4; ++kt){
      s16x8 ahi, alo;
      #pragma unroll
      for (int q = 0; q < 4; ++q){
        unsigned long long v = hwv[kt][q];
        unsigned w0 = (unsigned)v, w1 = (unsigned)(v >> 32);
        ahi[2 * q]     = (short)(unsigned short)(w0 & 0xFFFFu);
        alo[2 * q]     = (short)(unsigned short)(w0 >> 16);
        ahi[2 * q + 1] = (short)(unsigned short)(w1 & 0xFFFFu);
        alo[2 * q + 1] = (short)(unsigned short)(w1 >> 16);
      }
      #pragma unroll
      for (int g = 0; g < 4; ++g){
        acc[g] = __builtin_amdgcn_mfma_f32_16x16x32_bf16(ahi, Whi[kt][g], acc[g], 0, 0, 0);
        acc[g] = __builtin_amdgcn_mfma_f32_16x16x32_bf16(alo, Whi[kt][g], acc[g], 0, 0, 0);
        acc[g] = __builtin_amdgcn_mfma_f32_16x16x32_bf16(ahi, Wlo[kt][g], acc[g], 0, 0, 0);
      }
    }

    // ---- combine K-partials across waves (D layout: col=l15, row=4*kq+reg) ----
    #pragma unroll
    for (int g = 0; g < 4; ++g){
      #pragma unroll
      for (int r = 0; r < 4; ++r)
        atomicAdd(&exch[g * 256 + (4 * kq + r) * 16 + l15], acc[g][r]);
    }
    __syncthreads();

    // ---- epilogue: wave 0 does gates, updates c, publishes h(hi,lo) ----
    if (w == 0){
      #pragma unroll
      for (int r = 0; r < 4; ++r){
        const int bl = 4 * kq + r;
        float pi = exch[0 * 256 + bl * 16 + l15] + bias_r[0];
        float pf = exch[1 * 256 + bl * 16 + l15] + bias_r[1];
        float po = exch[2 * 256 + bl * 16 + l15] + bias_r[2];
        float pg = exch[3 * 256 + bl * 16 + l15] + bias_r[3];
        float c = sigm(pf) * cpriv[r] + sigm(pi) * tanh_f(pg);
        cpriv[r] = c;
        float h = sigm(po) * tanh_f(c);
        unsigned short hh = bf16_rne(h);
        unsigned short hl = bf16_rne(h - bf16_to_f(hh));
        unsigned word = (unsigned)hh | ((unsigned)hl << 16);
        __hip_atomic_store(hw_buf + (cur ^ 1u) * 65536u + (unsigned)(bbase + bl) * 512u + jglob,
                           word, __ATOMIC_RELAXED, __HIP_MEMORY_SCOPE_AGENT);
      }
    }

    // ---- per-group barrier (monotonic counter, release/acquire) ----
    if (tid == 0){
      __hip_atomic_fetch_add(cnt, 1u, __ATOMIC_RELEASE, __HIP_MEMORY_SCOPE_AGENT);
      const unsigned target = 32u * (unsigned)(t + 1);
      while (__hip_atomic_load(cnt, __ATOMIC_ACQUIRE, __HIP_MEMORY_SCOPE_AGENT) < target)
        __builtin_amdgcn_s_sleep(1);
    }
    __syncthreads();
    cur ^= 1u;
  }
}

// out = h_last @ Wo^T + bo   (h_last in hw_buf plane 0 after 2048 steps)
__global__ void out_proj_kernel(const unsigned* __restrict__ hw,
                                const float* __restrict__ Wo,
                                const float* __restrict__ bo,
                                float* __restrict__ out)
{
  __shared__ float hrow[512];
  const int b = blockIdx.x, tid = threadIdx.x;   // 128 threads
  for (int i = tid; i < 512; i += 128){
    unsigned wv = hw[b * 512 + i];
    hrow[i] = bf16_to_f((unsigned short)(wv & 0xFFFFu)) + bf16_to_f((unsigned short)(wv >> 16));
  }
  __syncthreads();
  float acc = bo[tid];
  const float* wrow = Wo + (size_t)tid * 512;
  #pragma unroll 4
  for (int k = 0; k < 512; k += 4){
    float4 wv = *(const float4*)(wrow + k);
    acc += wv.x * hrow[k] + wv.y * hrow[k + 1] + wv.z * hrow[k + 2] + wv.w * hrow[k + 3];
  }
  out[b * 128 + tid] = acc;
}

extern "C" void kernel_launch(void* const* d_in, const int* in_sizes, int n_in,
                              void* d_out, int out_size, void* d_ws, size_t ws_size,
                              hipStream_t stream)
{
  const float* x    = (const float*)d_in[0];
  const float* Wh   = (const float*)d_in[1];
  const float* Wx   = (const float*)d_in[2];
  const float* bias = (const float*)d_in[3];
  const float* Wo   = (const float*)d_in[4];
  const float* bo   = (const float*)d_in[5];
  float* out = (float*)d_out;

  unsigned* barriers = (unsigned*)d_ws;
  unsigned* hw       = (unsigned*)((char*)d_ws + 4096);

  // zero barrier counters + both h buffers (h0 = 0)
  hipMemsetAsync(d_ws, 0, 4096 + 2 * 128 * 512 * 4, stream);

  void* args[] = {(void*)&x, (void*)&Wh, (void*)&Wx, (void*)&bias, (void*)&hw, (void*)&barriers};
  hipError_t e = hipLaunchCooperativeKernel((void*)lstm_scan_kernel,
                                            dim3(256), dim3(256), args, 0, stream);
  if (e != hipSuccess){
    // fallback: plain launch (256 WGs x 256 thr trivially co-resident on 256 CUs)
    lstm_scan_kernel<<<dim3(256), dim3(256), 0, stream>>>(x, Wh, Wx, bias, hw, barriers);
  }

  out_proj_kernel<<<dim3(128), dim3(128), 0, stream>>>(hw, Wo, bo, out);
}

// Round 3
// 8293.662 us; speedup vs baseline: 3.3138x; 3.3138x over previous
//
#include <hip/hip_runtime.h>

typedef __attribute__((ext_vector_type(8))) short s16x8;
typedef __attribute__((ext_vector_type(4))) float f32x4;

#define S_LEN 2048
// ws layout: [0,4096)  barrier counters (8 groups, 256B stride)
//            [4096, 4096+2*128*512*4)  h double-buffer, u32 = (bf16_hi | bf16_lo<<16)

__device__ __forceinline__ unsigned short bf16_rne(float f){
  unsigned u = __builtin_bit_cast(unsigned, f);
  u += 0x7FFFu + ((u >> 16) & 1u);
  return (unsigned short)(u >> 16);
}
__device__ __forceinline__ float bf16_to_f(unsigned short h){
  unsigned u = ((unsigned)h) << 16;
  return __builtin_bit_cast(float, u);
}
__device__ __forceinline__ float sigm(float x){
  return 1.f / (1.f + __builtin_exp2f(-1.44269504f * x));
}
__device__ __forceinline__ float tanh_f(float x){
  float t = __builtin_exp2f(2.88539008f * x);
  return 1.f - 2.f / (t + 1.f);   // t->inf => 1, t->0 => -1
}

// split 8 consecutive fp32 into hi/lo bf16 fragments
__device__ __forceinline__ void split8(const float* __restrict__ src, s16x8& hi, s16x8& lo){
  const float4* p4 = (const float4*)src;
  float4 a = p4[0], b = p4[1];
  float v[8] = {a.x, a.y, a.z, a.w, b.x, b.y, b.z, b.w};
  #pragma unroll
  for (int e = 0; e < 8; ++e){
    unsigned short h = bf16_rne(v[e]);
    float r = v[e] - bf16_to_f(h);
    hi[e] = (short)h;
    lo[e] = (short)bf16_rne(r);
  }
}

// LDS exchange: [area a=wave][gate g][col=l15 (pad 20)][row bl 0..15]
// word idx: col stride 20 (pad) -> b128 writes 16B aligned, reads ~2-way banked
#define EX(a,g,c,r) ((((a)*4+(g))*320) + (c)*20 + (r))

__global__ void __launch_bounds__(256, 1)
lstm_scan_kernel(const float* __restrict__ x,
                 const float* __restrict__ Wh,
                 const float* __restrict__ Wx,
                 const float* __restrict__ bias,
                 unsigned* __restrict__ hw_buf,     // [2][128][512] u32 words
                 unsigned* __restrict__ barriers)   // 8 counters @ 256B stride
{
  __shared__ float exch[5120];                      // 20 KiB

  const int tid  = threadIdx.x;
  const int wg   = blockIdx.x;
  const int grp  = wg & 7;        // batch group (XCD-friendly hint only)
  const int sl   = wg >> 3;       // j-slice 0..31
  const int lane = tid & 63;
  const int w    = tid >> 6;      // wave 0..3 owns K-chunk [w*160, ...)
  const int l15  = lane & 15;     // A-row (batch-local) / B-col (j-local) / D-col
  const int kq   = lane >> 4;     // k quarter 0..3
  const int bbase = grp * 16;
  const int jglob = sl * 16 + l15;
  const int bl    = 4 * w + kq;   // this thread's epilogue batch-row

  // ---- persistent weight fragments in registers (split bf16 hi/lo) ----
  s16x8 Whi[4][4], Wlo[4][4];       // [kt][gate]
  s16x8 Xhi_w[4], Xlo_w[4];         // [gate]
  #pragma unroll
  for (int g = 0; g < 4; ++g){
    const int row = 512 * g + sl * 16 + l15;
    #pragma unroll
    for (int kt = 0; kt < 4; ++kt){
      const float* src = Wh + (size_t)row * 512 + (4 * w + kt) * 32 + kq * 8;
      split8(src, Whi[kt][g], Wlo[kt][g]);
    }
    const float* sx = Wx + (size_t)row * 128 + w * 32 + kq * 8;
    split8(sx, Xhi_w[g], Xlo_w[g]);
  }

  float bias_r[4];
  #pragma unroll
  for (int g = 0; g < 4; ++g) bias_r[g] = bias[512 * g + jglob];

  float cpriv = 0.f;   // c for (b = bbase+bl, j = jglob)
  unsigned* cnt = (unsigned*)((char*)barriers + grp * 256);
  unsigned cur = 0;

  // prologue: x fragments for t=0
  s16x8 xhi, xlo;
  split8(x + ((size_t)(bbase + l15) * S_LEN + 0) * 128 + w * 32 + kq * 8, xhi, xlo);

  for (int t = 0; t < S_LEN; ++t){
    // ---- h loads (relaxed agent: execute at L3 coherence point) ----
    unsigned long long hwv[4][4];
    unsigned* hb = hw_buf + cur * 65536u + (unsigned)(bbase + l15) * 512u;
    #pragma unroll
    for (int kt = 0; kt < 4; ++kt){
      unsigned long long* p = (unsigned long long*)(hb + (4 * w + kt) * 32 + kq * 8);
      #pragma unroll
      for (int q = 0; q < 4; ++q)
        hwv[kt][q] = __hip_atomic_load(p + q, __ATOMIC_RELAXED, __HIP_MEMORY_SCOPE_AGENT);
    }

    f32x4 acc[4];
    #pragma unroll
    for (int g = 0; g < 4; ++g){ f32x4 z = {0.f, 0.f, 0.f, 0.f}; acc[g] = z; }

    // ---- x part (preloaded frags; overlaps h-load latency) ----
    #pragma unroll
    for (int g = 0; g < 4; ++g){
      acc[g] = __builtin_amdgcn_mfma_f32_16x16x32_bf16(xhi, Xhi_w[g], acc[g], 0, 0, 0);
      acc[g] = __builtin_amdgcn_mfma_f32_16x16x32_bf16(xlo, Xhi_w[g], acc[g], 0, 0, 0);
      acc[g] = __builtin_amdgcn_mfma_f32_16x16x32_bf16(xhi, Xlo_w[g], acc[g], 0, 0, 0);
    }

    // ---- h part: unpack words -> hi/lo A-frags, 3 split products ----
    #pragma unroll
    for (int kt = 0; kt < 4; ++kt){
      s16x8 ahi, alo;
      #pragma unroll
      for (int q = 0; q < 4; ++q){
        unsigned long long v = hwv[kt][q];
        unsigned w0 = (unsigned)v, w1 = (unsigned)(v >> 32);
        ahi[2 * q]     = (short)(unsigned short)(w0 & 0xFFFFu);
        alo[2 * q]     = (short)(unsigned short)(w0 >> 16);
        ahi[2 * q + 1] = (short)(unsigned short)(w1 & 0xFFFFu);
        alo[2 * q + 1] = (short)(unsigned short)(w1 >> 16);
      }
      #pragma unroll
      for (int g = 0; g < 4; ++g){
        acc[g] = __builtin_amdgcn_mfma_f32_16x16x32_bf16(ahi, Whi[kt][g], acc[g], 0, 0, 0);
        acc[g] = __builtin_amdgcn_mfma_f32_16x16x32_bf16(alo, Whi[kt][g], acc[g], 0, 0, 0);
        acc[g] = __builtin_amdgcn_mfma_f32_16x16x32_bf16(ahi, Wlo[kt][g], acc[g], 0, 0, 0);
      }
    }

    // ---- per-wave partials to LDS (b128, no atomics) ----
    // acc[g][r] = D[row=4*kq+r][col=l15]; rows contiguous in EX layout
    #pragma unroll
    for (int g = 0; g < 4; ++g)
      *(f32x4*)&exch[EX(w, g, l15, 4 * kq)] = acc[g];
    __syncthreads();

    // ---- epilogue distributed over all 256 threads (1 value each) ----
    {
      float p[4];
      #pragma unroll
      for (int g = 0; g < 4; ++g)
        p[g] = bias_r[g]
             + exch[EX(0, g, l15, bl)] + exch[EX(1, g, l15, bl)]
             + exch[EX(2, g, l15, bl)] + exch[EX(3, g, l15, bl)];
      float c = sigm(p[1]) * cpriv + sigm(p[0]) * tanh_f(p[3]);
      cpriv = c;
      float h = sigm(p[2]) * tanh_f(c);
      unsigned short hh = bf16_rne(h);
      unsigned short hl = bf16_rne(h - bf16_to_f(hh));
      unsigned word = (unsigned)hh | ((unsigned)hl << 16);
      __hip_atomic_store(hw_buf + (cur ^ 1u) * 65536u + (unsigned)(bbase + bl) * 512u + jglob,
                         word, __ATOMIC_RELAXED, __HIP_MEMORY_SCOPE_AGENT);
    }

    // writer-side ordering: h stores acked at coherence point before counter bump
    asm volatile("s_waitcnt vmcnt(0)" ::: "memory");
    __syncthreads();

    if (tid == 0)
      __hip_atomic_fetch_add(cnt, 1u, __ATOMIC_RELAXED, __HIP_MEMORY_SCOPE_AGENT);

    // prefetch + split next x while tid0's counter bump / spin are in flight
    {
      const int tn = (t + 1 < S_LEN) ? t + 1 : t;
      split8(x + ((size_t)(bbase + l15) * S_LEN + tn) * 128 + w * 32 + kq * 8, xhi, xlo);
    }

    if (tid == 0){
      const unsigned target = 32u * (unsigned)(t + 1);
      while (__hip_atomic_load(cnt, __ATOMIC_RELAXED, __HIP_MEMORY_SCOPE_AGENT) < target) {}
    }
    __syncthreads();
    cur ^= 1u;
  }
}

// out = h_last @ Wo^T + bo   (h_last in hw_buf plane 0 after 2048 steps)
__global__ void out_proj_kernel(const unsigned* __restrict__ hw,
                                const float* __restrict__ Wo,
                                const float* __restrict__ bo,
                                float* __restrict__ out)
{
  __shared__ float hrow[512];
  const int b = blockIdx.x, tid = threadIdx.x;   // 128 threads
  for (int i = tid; i < 512; i += 128){
    unsigned wv = hw[b * 512 + i];
    hrow[i] = bf16_to_f((unsigned short)(wv & 0xFFFFu)) + bf16_to_f((unsigned short)(wv >> 16));
  }
  __syncthreads();
  float acc = bo[tid];
  const float* wrow = Wo + (size_t)tid * 512;
  #pragma unroll 4
  for (int k = 0; k < 512; k += 4){
    float4 wv = *(const float4*)(wrow + k);
    acc += wv.x * hrow[k] + wv.y * hrow[k + 1] + wv.z * hrow[k + 2] + wv.w * hrow[k + 3];
  }
  out[b * 128 + tid] = acc;
}

extern "C" void kernel_launch(void* const* d_in, const int* in_sizes, int n_in,
                              void* d_out, int out_size, void* d_ws, size_t ws_size,
                              hipStream_t stream)
{
  const float* x    = (const float*)d_in[0];
  const float* Wh   = (const float*)d_in[1];
  const float* Wx   = (const float*)d_in[2];
  const float* bias = (const float*)d_in[3];
  const float* Wo   = (const float*)d_in[4];
  const float* bo   = (const float*)d_in[5];
  float* out = (float*)d_out;

  unsigned* barriers = (unsigned*)d_ws;
  unsigned* hw       = (unsigned*)((char*)d_ws + 4096);

  // zero barrier counters + both h buffers (h0 = 0)
  hipMemsetAsync(d_ws, 0, 4096 + 2 * 128 * 512 * 4, stream);

  void* args[] = {(void*)&x, (void*)&Wh, (void*)&Wx, (void*)&bias, (void*)&hw, (void*)&barriers};
  hipError_t e = hipLaunchCooperativeKernel((void*)lstm_scan_kernel,
                                            dim3(256), dim3(256), args, 0, stream);
  if (e != hipSuccess){
    lstm_scan_kernel<<<dim3(256), dim3(256), 0, stream>>>(x, Wh, Wx, bias, hw, barriers);
  }

  out_proj_kernel<<<dim3(128), dim3(128), 0, stream>>>(hw, Wo, bo, out);
}

// Round 8
// 5255.682 us; speedup vs baseline: 5.2293x; 1.5780x over previous
//
#include <hip/hip_runtime.h>

typedef __attribute__((ext_vector_type(8))) short s16x8;
typedef __attribute__((ext_vector_type(4))) float f32x4;

#define S_LEN 2048
#define DEPTH 4
#define SPIN_CAP (1 << 20)   // failsafe: wrong-result beats GPU hang
// ws layout: [0, DEPTH*65536*4)  h ring, u32 = (bf16(h)<<16)|(step&0xFFFF),
//            layout [slot][j=512][b=128] (65536 words/slot), init 0 (= h0, tag 0).
// Protocol: tag-in-word only. A WG reaches step t only after ALL peers wrote h_t
// (tag t present in every word), which implies every peer consumed h_{t-1} and
// earlier. Writer at step t overwrites slot (t+1)&3 holding h_{t-3} — already
// consumed by all peers (they are at step >= t-1). No barrier/gate needed.

__device__ __forceinline__ unsigned short bf16_rne(float f){
  unsigned u = __builtin_bit_cast(unsigned, f);
  u += 0x7FFFu + ((u >> 16) & 1u);
  return (unsigned short)(u >> 16);
}
__device__ __forceinline__ float bf16_to_f(unsigned short h){
  unsigned u = ((unsigned)h) << 16;
  return __builtin_bit_cast(float, u);
}
__device__ __forceinline__ float sigm(float x){
  return 1.f / (1.f + __builtin_exp2f(-1.44269504f * x));
}
__device__ __forceinline__ float tanh_f(float x){
  float t = __builtin_exp2f(2.88539008f * x);
  return 1.f - 2.f / (t + 1.f);   // t->inf => 1, t->0 => -1
}

__device__ __forceinline__ void split8(const float* __restrict__ src, s16x8& hi, s16x8& lo){
  const float4* p4 = (const float4*)src;
  float4 a = p4[0], b = p4[1];
  float v[8] = {a.x, a.y, a.z, a.w, b.x, b.y, b.z, b.w};
  #pragma unroll
  for (int e = 0; e < 8; ++e){
    unsigned short h = bf16_rne(v[e]);
    float r = v[e] - bf16_to_f(h);
    hi[e] = (short)h;
    lo[e] = (short)bf16_rne(r);
  }
}

// LDS exchange: [area a=wave][gate g][col=l15 (stride 20 pad)][row bl 0..15]
#define EX(a,g,c,r) ((((a)*4+(g))*320) + (c)*20 + (r))

__global__ void __launch_bounds__(256, 1)
lstm_scan_kernel(const float* __restrict__ x,
                 const float* __restrict__ Wh,
                 const float* __restrict__ Wx,
                 const float* __restrict__ bias,
                 unsigned* __restrict__ hq)         // [DEPTH][512][128] u32
{
  __shared__ float exch[5120];                      // 20 KiB

  const int tid  = threadIdx.x;
  const int wg   = blockIdx.x;
  const int grp  = wg & 7;        // batch group
  const int sl   = wg >> 3;       // j-slice 0..31
  const int lane = tid & 63;
  const int w    = tid >> 6;      // wave 0..3 owns j-chunk [w*128, ...)
  const int l15  = lane & 15;     // A-row (batch-local) / B-col (j-local) / D-col
  const int kq   = lane >> 4;     // k quarter 0..3
  const int bbase = grp * 16;
  const int jglob = sl * 16 + l15;
  const int bl    = 4 * w + kq;   // this thread's epilogue batch-row

  // ---- persistent weight fragments in registers (split bf16 hi/lo) ----
  s16x8 Whi[4][4], Wlo[4][4];       // [kt][gate]
  s16x8 Xhi_w[4], Xlo_w[4];         // [gate]
  #pragma unroll
  for (int g = 0; g < 4; ++g){
    const int row = 512 * g + sl * 16 + l15;
    #pragma unroll
    for (int kt = 0; kt < 4; ++kt){
      const float* src = Wh + (size_t)row * 512 + (4 * w + kt) * 32 + kq * 8;
      split8(src, Whi[kt][g], Wlo[kt][g]);
    }
    const float* sx = Wx + (size_t)row * 128 + w * 32 + kq * 8;
    split8(sx, Xhi_w[g], Xlo_w[g]);
  }

  float bias_r[4];
  #pragma unroll
  for (int g = 0; g < 4; ++g) bias_r[g] = bias[512 * g + jglob];

  float cpriv = 0.f;   // c for (b = bbase+bl, j = jglob)

  // prologue: x fragments for t=0
  s16x8 xhi, xlo;
  split8(x + ((size_t)(bbase + l15) * S_LEN + 0) * 128 + w * 32 + kq * 8, xhi, xlo);

  for (int t = 0; t < S_LEN; ++t){
    const unsigned slot = (unsigned)t & (DEPTH - 1);
    // ---- issue h loads: 32 coalesced u32/lane, word idx = slot*65536 + j*128 + b ----
    // j = w*128 + kt*32 + kq*8 + e
    unsigned hv[4][8];
    const unsigned hbase = slot * 65536u
                         + (unsigned)(w * 16384 + kq * 1024 + bbase + l15);
    #pragma unroll
    for (int kt = 0; kt < 4; ++kt)
      #pragma unroll
      for (int e = 0; e < 8; ++e)
        hv[kt][e] = __hip_atomic_load(hq + hbase + kt * 4096 + e * 128,
                                      __ATOMIC_RELAXED, __HIP_MEMORY_SCOPE_AGENT);

    f32x4 acc[4];
    #pragma unroll
    for (int g = 0; g < 4; ++g){ f32x4 z = {0.f, 0.f, 0.f, 0.f}; acc[g] = z; }

    // ---- x part (preloaded frags; overlaps h-load latency) ----
    #pragma unroll
    for (int g = 0; g < 4; ++g){
      acc[g] = __builtin_amdgcn_mfma_f32_16x16x32_bf16(xhi, Xhi_w[g], acc[g], 0, 0, 0);
      acc[g] = __builtin_amdgcn_mfma_f32_16x16x32_bf16(xlo, Xhi_w[g], acc[g], 0, 0, 0);
      acc[g] = __builtin_amdgcn_mfma_f32_16x16x32_bf16(xhi, Xlo_w[g], acc[g], 0, 0, 0);
    }

    // ---- tag spin: load IS the detect; payload+tag arrive in one atomic word ----
    const unsigned etag = (unsigned)t & 0xFFFFu;
    int spin = 0;
    for (;;){
      int ok = 1;
      #pragma unroll
      for (int kt = 0; kt < 4; ++kt)
        #pragma unroll
        for (int e = 0; e < 8; ++e)
          ok &= (((hv[kt][e] ^ etag) & 0xFFFFu) == 0u);
      if (__all(ok)) break;
      if (++spin > SPIN_CAP) break;   // failsafe (detectable wrong result, no hang)
      __builtin_amdgcn_s_sleep(1);
      #pragma unroll
      for (int kt = 0; kt < 4; ++kt)
        #pragma unroll
        for (int e = 0; e < 8; ++e)
          hv[kt][e] = __hip_atomic_load(hq + hbase + kt * 4096 + e * 128,
                                        __ATOMIC_RELAXED, __HIP_MEMORY_SCOPE_AGENT);
    }

    // ---- h part: unpack hi bf16, 2 split products (hi*Whi + hi*Wlo) ----
    #pragma unroll
    for (int kt = 0; kt < 4; ++kt){
      s16x8 ahi;
      #pragma unroll
      for (int e = 0; e < 8; ++e)
        ahi[e] = (short)(hv[kt][e] >> 16);
      #pragma unroll
      for (int g = 0; g < 4; ++g){
        acc[g] = __builtin_amdgcn_mfma_f32_16x16x32_bf16(ahi, Whi[kt][g], acc[g], 0, 0, 0);
        acc[g] = __builtin_amdgcn_mfma_f32_16x16x32_bf16(ahi, Wlo[kt][g], acc[g], 0, 0, 0);
      }
    }

    // ---- per-wave partials to LDS (b128, no atomics) ----
    #pragma unroll
    for (int g = 0; g < 4; ++g)
      *(f32x4*)&exch[EX(w, g, l15, 4 * kq)] = acc[g];
    __syncthreads();

    // ---- epilogue distributed over all 256 threads (1 value each) ----
    {
      float p[4];
      #pragma unroll
      for (int g = 0; g < 4; ++g)
        p[g] = bias_r[g]
             + exch[EX(0, g, l15, bl)] + exch[EX(1, g, l15, bl)]
             + exch[EX(2, g, l15, bl)] + exch[EX(3, g, l15, bl)];
      float c = sigm(p[1]) * cpriv + sigm(p[0]) * tanh_f(p[3]);
      cpriv = c;
      float h = sigm(p[2]) * tanh_f(c);
      unsigned short hh = bf16_rne(h);
      unsigned word = ((unsigned)hh << 16) | ((unsigned)(t + 1) & 0xFFFFu);
      const unsigned widx = ((unsigned)(t + 1) & (DEPTH - 1)) * 65536u
                          + (unsigned)(jglob * 128 + bbase + bl);
      __hip_atomic_store(hq + widx, word, __ATOMIC_RELAXED, __HIP_MEMORY_SCOPE_AGENT);
    }

    // prefetch + split next x (overlaps stores / next-step polls)
    {
      const int tn = (t + 1 < S_LEN) ? t + 1 : t;
      split8(x + ((size_t)(bbase + l15) * S_LEN + tn) * 128 + w * 32 + kq * 8, xhi, xlo);
    }
    __syncthreads();   // exch reuse fence
  }
}

// out = h_last @ Wo^T + bo   (h_2048 in ring slot 2048&3 = 0)
__global__ void out_proj_kernel(const unsigned* __restrict__ hq,
                                const float* __restrict__ Wo,
                                const float* __restrict__ bo,
                                float* __restrict__ out)
{
  __shared__ float hrow[512];
  const int b = blockIdx.x, tid = threadIdx.x;   // 128 threads
  for (int i = tid; i < 512; i += 128)
    hrow[i] = bf16_to_f((unsigned short)(hq[i * 128 + b] >> 16));
  __syncthreads();
  float acc = bo[tid];
  const float* wrow = Wo + (size_t)tid * 512;
  #pragma unroll 4
  for (int k = 0; k < 512; k += 4){
    float4 wv = *(const float4*)(wrow + k);
    acc += wv.x * hrow[k] + wv.y * hrow[k + 1] + wv.z * hrow[k + 2] + wv.w * hrow[k + 3];
  }
  out[b * 128 + tid] = acc;
}

extern "C" void kernel_launch(void* const* d_in, const int* in_sizes, int n_in,
                              void* d_out, int out_size, void* d_ws, size_t ws_size,
                              hipStream_t stream)
{
  const float* x    = (const float*)d_in[0];
  const float* Wh   = (const float*)d_in[1];
  const float* Wx   = (const float*)d_in[2];
  const float* bias = (const float*)d_in[3];
  const float* Wo   = (const float*)d_in[4];
  const float* bo   = (const float*)d_in[5];
  float* out = (float*)d_out;

  unsigned* hq = (unsigned*)d_ws;

  // h ring init 0 = (h0 payload 0, tag 0)
  hipMemsetAsync(hq, 0, (size_t)DEPTH * 65536 * 4, stream);

  void* args[] = {(void*)&x, (void*)&Wh, (void*)&Wx, (void*)&bias, (void*)&hq};
  hipError_t e = hipLaunchCooperativeKernel((void*)lstm_scan_kernel,
                                            dim3(256), dim3(256), args, 0, stream);
  if (e != hipSuccess){
    lstm_scan_kernel<<<dim3(256), dim3(256), 0, stream>>>(x, Wh, Wx, bias, hq);
  }

  out_proj_kernel<<<dim3(128), dim3(128), 0, stream>>>(hq, Wo, bo, out);
}